// Round 7
// baseline (558.318 us; speedup 1.0000x reference)
//
#include <hip/hip_runtime.h>
#include <hip/hip_bf16.h>
#include <stdint.h>

typedef __hip_bfloat16 bf;
typedef __attribute__((ext_vector_type(8))) short short8;
typedef __attribute__((ext_vector_type(4))) float float4v;
__device__ __forceinline__ float b2f(bf x){ return __bfloat162float(x); }
__device__ __forceinline__ float sane(float x){ return fminf(fmaxf(x, -1e6f), 1e6f); }
__device__ __forceinline__ short f2b(float f){
    uint32_t u = __float_as_uint(f);
    u += 0x7fffu + ((u >> 16) & 1u);
    return (short)(u >> 16);
}

// Problem constants
constexpr int N   = 6144;          // NOT a power of two (3*2^11)!
constexpr int D   = 64;
constexpr int FE  = 32;
constexpr int Eg  = 196608;        // < 2^18 -> edge id packs in 18 bits
constexpr size_t NF = (size_t)N * D;

__device__ __forceinline__ int clampi(int v){ return v < 0 ? 0 : (v >= N ? N - 1 : v); }
__device__ __forceinline__ float ldf(const void* p, size_t i, uint32_t isf32){
    return isf32 ? ((const float*)p)[i] : b2f(((const bf*)p)[i]);
}

// ---- float workspace layout (floats) ----  ~19.2 MB
constexpr size_t OF_O    = 0;                           // [2][N][D] attn numerator (atomic)
constexpr size_t OF_L    = OF_O + 2*NF;                 // [2][N]
constexpr size_t OF_MEAN = OF_L + 2*(size_t)N;          // [2][N][D]
constexpr size_t OF_POOL = OF_MEAN + 2*NF;              // [4][N][FE]
constexpr size_t OF_QKVB = OF_POOL + (size_t)4*N*FE;    // bf16 [2][3][N][D] (Q pre-scaled)
constexpr size_t OF_XF   = OF_QKVB + 3*NF;              // [2][N][D] f32 staged x1,x2
constexpr size_t OF_WA   = OF_XF + 2*NF;                // [6][64][64]
constexpr size_t OF_BA   = OF_WA + 24576;               // [6][64]
constexpr size_t OF_WO   = OF_BA + 384;                 // [2][64][64]
constexpr size_t OF_BO   = OF_WO + 8192;                // [2][64]
constexpr size_t OF_WF   = OF_BO + 128;                 // [384][64]
constexpr size_t OF_BF   = OF_WF + 24576;               // [64]
constexpr size_t OF_VT   = OF_BF + 64;                  // bf16 [2][64][N] = V^T slabs
constexpr size_t F_TOTAL = OF_VT + 393216;
// ---- u32 workspace (words, after float region) ----  ~3.44 MB
constexpr size_t OI_CNT  = 0;                           // [4][N]
constexpr size_t OI_PTR  = OI_CNT + 4*(size_t)N;        // [4][N+1]
constexpr size_t OI_CUR  = OI_PTR + 4*(size_t)(N+1);    // [4][N]
constexpr size_t OI_PAY  = OI_CUR + 4*(size_t)N;        // [4][Eg]  e | (other<<18)
constexpr size_t OI_FLAG = OI_PAY + 4*(size_t)Eg;       // [4] dtype flags

constexpr int NZF = (int)(2*NF + 2*(size_t)N);          // O + L floats to zero (798720)

// ---- K1: zero O/L + zero CSR counts + dtype sniff ----
__global__ void prep0_kernel(const void* xA, const void* xB, const void* xC, const void* xD,
                             float* __restrict__ fz, uint32_t* __restrict__ uz,
                             uint32_t* __restrict__ flags){
    int b = blockIdx.x, t = threadIdx.x;
    if (b < 3120){
        int i = b * 256 + t;
        if (i < NZF) fz[i] = 0.f;
    } else if (b < 3216){
        int i = (b - 3120) * 256 + t;
        if (i < 24576) uz[i] = 0u;
    } else {
        __shared__ float red[256];
        const void* ps[4] = {xA, xB, xC, xD};
        for (int k = 0; k < 4; ++k){
            const bf* p = (const bf*)ps[k];
            float m = 0.f;
            for (int i = t; i < 1024; i += 256){
                float v = fabsf(b2f(p[i]));
                if (!(v <= 1e9f)) v = 1e9f;
                m = fmaxf(m, v);
            }
            red[t] = m; __syncthreads();
            for (int off = 128; off; off >>= 1){
                if (t < off) red[t] = fmaxf(red[t], red[t + off]);
                __syncthreads();
            }
            if (t == 0) flags[k] = (red[0] > 100.f) ? 1u : 0u;
            __syncthreads();
        }
    }
}

// ---- K2: convert (x, attn W/b, final W/b) + CSR degree counts ----
__global__ void prep1_kernel(const void* x1, const void* x2,
                             const void* W0, const void* W1, const void* W2,
                             const void* W3, const void* W4, const void* W5,
                             const void* B0, const void* B1, const void* B2,
                             const void* B3, const void* B4, const void* B5,
                             const void* Wop, const void* bop,
                             const void* Won, const void* bon,
                             const void* wgt, const void* bia,
                             const int* __restrict__ eip, const int* __restrict__ ein,
                             const uint32_t* __restrict__ flags,
                             float* __restrict__ ws, uint32_t* __restrict__ iws){
    int b = blockIdx.x, t = threadIdx.x;
    if (b < 3072){
        size_t idx = (size_t)b * 256 + t;
        uint32_t fA = flags[0];
        float v = (idx < NF) ? ldf(x1, idx, fA) : ldf(x2, idx - NF, fA);
        ws[OF_XF + idx] = sane(v);
    } else if (b < 3202){
        size_t idx = (size_t)(b - 3072) * 256 + t;
        if (idx >= 33280) return;
        uint32_t fD = flags[3];
        float v;
        if (idx < 24576){
            int m = (int)(idx >> 12), sub = (int)(idx & 4095);
            const void* W = (m==0)?W0:(m==1)?W1:(m==2)?W2:(m==3)?W3:(m==4)?W4:W5;
            v = ldf(W, sub, fD);
        } else if (idx < 24960){
            int m = (int)((idx - 24576) >> 6), sub = (int)(idx & 63);
            const void* B = (m==0)?B0:(m==1)?B1:(m==2)?B2:(m==3)?B3:(m==4)?B4:B5;
            v = ldf(B, sub, fD);
        } else if (idx < 33152){
            int k = (int)((idx - 24960) >> 12), sub = (int)(idx & 4095);
            v = ldf(k ? Won : Wop, sub, fD);
        } else {
            int k = (int)((idx - 33152) >> 6), sub = (int)(idx & 63);
            v = ldf(k ? bon : bop, sub, fD);
        }
        ws[OF_WA + idx] = sane(v);
    } else if (b < 3299){
        size_t idx = (size_t)(b - 3202) * 256 + t;
        if (idx >= 24640) return;
        uint32_t fC = flags[2];
        float v = (idx < 24576) ? ldf(wgt, idx, fC) : ldf(bia, idx - 24576, fC);
        ws[OF_WF + idx] = sane(v);
    } else {
        int e = (b - 3299) * 256 + t;
        if (e >= Eg) return;
        uint32_t* cnt = iws + OI_CNT;
        atomicAdd(&cnt[0 * N + clampi(eip[e])],      1u);
        atomicAdd(&cnt[1 * N + clampi(eip[Eg + e])], 1u);
        atomicAdd(&cnt[2 * N + clampi(ein[e])],      1u);
        atomicAdd(&cnt[3 * N + clampi(ein[Eg + e])], 1u);
    }
}

__global__ void scan_kernel(uint32_t* __restrict__ iws){
    int b = blockIdx.x, t = threadIdx.x;
    const uint32_t* c = iws + OI_CNT + (size_t)b * N;
    uint32_t* P  = iws + OI_PTR + (size_t)b * (N + 1);
    uint32_t* Cu = iws + OI_CUR + (size_t)b * N;
    constexpr int K = N / 256;
    int base = t * K;
    uint32_t s = 0;
    for (int k = 0; k < K; ++k) s += c[base + k];
    __shared__ uint32_t sums[256];
    sums[t] = s; __syncthreads();
    for (int off = 1; off < 256; off <<= 1){
        uint32_t v = (t >= off) ? sums[t - off] : 0u;
        __syncthreads();
        sums[t] += v;
        __syncthreads();
    }
    uint32_t run = (t == 0) ? 0u : sums[t - 1];
    for (int k = 0; k < K; ++k){ P[base + k] = run; Cu[base + k] = run; run += c[base + k]; }
    if (t == 255) P[N] = run;
}

// ---- K4: CSR fill + QKV projections ----
__global__ void fillqkv_kernel(const int* __restrict__ eip, const int* __restrict__ ein,
                               uint32_t* __restrict__ iws, float* __restrict__ ws){
    int b = blockIdx.x;
    if (b < 768){
        int e = b * 256 + threadIdx.x;
        if (e >= Eg) return;
        uint32_t* Cu  = iws + OI_CUR;
        uint32_t* Pay = iws + OI_PAY;
        int rp = clampi(eip[e]), cp = clampi(eip[Eg + e]);
        int rn = clampi(ein[e]), cn = clampi(ein[Eg + e]);
        uint32_t p;
        p = atomicAdd(&Cu[0 * N + rp], 1u); if (p < Eg) Pay[0 * (size_t)Eg + p] = (uint32_t)e | ((uint32_t)cp << 18);
        p = atomicAdd(&Cu[1 * N + cp], 1u); if (p < Eg) Pay[1 * (size_t)Eg + p] = (uint32_t)e | ((uint32_t)rp << 18);
        p = atomicAdd(&Cu[2 * N + rn], 1u); if (p < Eg) Pay[2 * (size_t)Eg + p] = (uint32_t)e | ((uint32_t)cn << 18);
        p = atomicAdd(&Cu[3 * N + cn], 1u); if (p < Eg) Pay[3 * (size_t)Eg + p] = (uint32_t)e | ((uint32_t)rn << 18);
    } else {
        int bb = b - 768;
        int m = bb / 1536, ib = bb - m * 1536;
        int wid = threadIdx.x >> 6, lane = threadIdx.x & 63;
        int i = ib * 4 + wid;
        const float* x = ws + OF_XF + (m < 3 ? 0 : NF) + (size_t)i * 64;
        const float* W = ws + OF_WA + (size_t)m * 4096;
        float xreg = x[lane];
        float acc = ws[OF_BA + m * 64 + lane];
        #pragma unroll 16
        for (int d = 0; d < 64; ++d)
            acc += __shfl(xreg, d, 64) * W[d * 64 + lane];
        acc = sane(acc);
        if (m == 0 || m == 3) acc *= 0.125f;   // fold softmax scale into Q
        bf* qkvb = (bf*)(ws + OF_QKVB);
        qkvb[(size_t)m * NF + (size_t)i * 64 + lane] = __float2bfloat16(acc);
    }
}

// ---- K5: V -> V^T (bf16), 64x64 LDS tiles ----
__global__ void transpose_kernel(float* __restrict__ ws){
    const bf* qkvb = (const bf*)(ws + OF_QKVB);
    bf* vt = (bf*)(ws + OF_VT);
    int b = blockIdx.x;               // 0..191
    int sg = b / 96, tile = b - sg * 96;
    const bf* Vb = qkvb + (size_t)(sg * 3 + 2) * NF;
    bf* Vt = vt + (size_t)sg * 64 * N;
    __shared__ short T[64][72];
    int t = threadIdx.x;
    int row = t >> 2, ch = t & 3;
    const short* src = (const short*)(Vb + (size_t)(tile * 64 + row) * 64 + ch * 16);
    short8 a = *(const short8*)src;
    short8 c = *(const short8*)(src + 8);
    #pragma unroll
    for (int j = 0; j < 8; ++j){ T[row][ch * 16 + j] = a[j]; T[row][ch * 16 + 8 + j] = c[j]; }
    __syncthreads();
    int d = t >> 2;
    short8 o0, o1;
    #pragma unroll
    for (int j = 0; j < 8; ++j){ o0[j] = T[ch * 16 + j][d]; o1[j] = T[ch * 16 + 8 + j][d]; }
    short* dst = (short*)(Vt + (size_t)d * N + tile * 64 + ch * 16);
    *(short8*)dst = o0;
    *(short8*)(dst + 8) = o1;
}

// ---- K6: dense unmasked attention, barrier-free, all operands from global ----
// p = exp(s+1) everywhere; edge/diag fixed by corr_role. S^T tiling: lane&15 = q-row.
__global__ void __launch_bounds__(256, 4)
attn_dense_kernel(const float* __restrict__ ws_ro, float* __restrict__ O,
                  float* __restrict__ Lg){
    constexpr int PP = 36;
    __shared__ __align__(16) float Pl[4][16 * PP];   // per-wave P round-trip, 9.2 KB
    int tid = threadIdx.x, lane = tid & 63, wv = tid >> 6;
    int m16 = lane & 15, quad = lane >> 4;
    int rt = blockIdx.x, cs = blockIdx.y, sg = blockIdx.z;
    const bf* qkvb = (const bf*)(ws_ro + OF_QKVB);
    const bf* Qb = qkvb + (size_t)(sg * 3) * NF;
    const bf* Kb = Qb + NF;
    const bf* Vt = (const bf*)(ws_ro + OF_VT) + (size_t)sg * 64 * N;

    int rowbase = rt * 64 + wv * 16;
    short8 Qf0 = *(const short8*)(Qb + (size_t)(rowbase + m16) * 64 + quad * 8);
    short8 Qf1 = *(const short8*)(Qb + (size_t)(rowbase + m16) * 64 + 32 + quad * 8);

    float4v Oc[4];
    #pragma unroll
    for (int t = 0; t < 4; ++t) Oc[t] = (float4v){0.f, 0.f, 0.f, 0.f};
    float l = 0.f;
    float* Pw = Pl[wv];

    int c0 = cs * (N / 8);
    for (int cb = c0; cb < c0 + N / 8; cb += 64){
        #pragma unroll
        for (int kg = 0; kg < 2; ++kg){
            #pragma unroll
            for (int ct = 0; ct < 2; ++ct){
                int col = cb + kg * 32 + ct * 16 + m16;
                short8 A0 = *(const short8*)(Kb + (size_t)col * 64 + quad * 8);
                short8 A1 = *(const short8*)(Kb + (size_t)col * 64 + 32 + quad * 8);
                float4v s = __builtin_amdgcn_mfma_f32_16x16x32_bf16(
                                A0, Qf0, (float4v){0.f,0.f,0.f,0.f}, 0, 0, 0);
                s = __builtin_amdgcn_mfma_f32_16x16x32_bf16(A1, Qf1, s, 0, 0, 0);
                float4v pv;
                #pragma unroll
                for (int r = 0; r < 4; ++r){
                    pv[r] = __expf(s[r] + 1.0f);
                    l += pv[r];
                }
                *(float4v*)(&Pw[m16 * PP + ct * 16 + quad * 4]) = pv;
            }
            asm volatile("s_waitcnt lgkmcnt(0)" ::: "memory");
            float4v pa = *(const float4v*)(&Pw[m16 * PP + quad * 8]);
            float4v pb = *(const float4v*)(&Pw[m16 * PP + quad * 8 + 4]);
            short8 Pf;
            #pragma unroll
            for (int j = 0; j < 4; ++j){ Pf[j] = f2b(pa[j]); Pf[4 + j] = f2b(pb[j]); }
            #pragma unroll
            for (int dt = 0; dt < 4; ++dt){
                short8 Va = *(const short8*)(Vt + (size_t)(dt * 16 + m16) * N + cb + kg * 32 + quad * 8);
                Oc[dt] = __builtin_amdgcn_mfma_f32_16x16x32_bf16(Va, Pf, Oc[dt], 0, 0, 0);
            }
        }
    }
    l += __shfl_xor(l, 16, 64);
    l += __shfl_xor(l, 32, 64);
    if (quad == 0) atomicAdd(&Lg[(size_t)sg * N + rowbase + m16], l);
    float* Op = O + ((size_t)sg * N + rowbase + m16) * 64;
    #pragma unroll
    for (int dt = 0; dt < 4; ++dt)
        #pragma unroll
        for (int r = 0; r < 4; ++r)
            atomicAdd(&Op[dt * 16 + quad * 4 + r], Oc[dt][r]);
}

// ---- mega kernel roles (verified round 6) ----
__device__ __forceinline__ void mean_role(int b, const uint32_t* __restrict__ iws,
                                          const float* __restrict__ ws_ro, float* __restrict__ ws){
    int wid = threadIdx.x >> 6, d = threadIdx.x & 63;
    int gw = b * 4 + wid;
    int sign = gw >= N;
    int i = gw - sign * N;
    const float* x = ws_ro + OF_XF + (size_t)sign * NF;
    int csr = sign ? 2 : 0;
    const uint32_t* P   = iws + OI_PTR + (size_t)csr * (N + 1);
    const uint32_t* Pay = iws + OI_PAY + (size_t)csr * Eg;
    float acc = x[(size_t)i * 64 + d];
    uint32_t p0 = P[i], p1 = P[i + 1];
    if (p1 > (uint32_t)Eg) p1 = Eg;
    if (p0 > p1) p0 = p1;
    uint32_t p = p0;
    for (; p + 4 <= p1; p += 4){
        int c0 = (int)(Pay[p]     >> 18);
        int c1 = (int)(Pay[p + 1] >> 18);
        int c2 = (int)(Pay[p + 2] >> 18);
        int c3 = (int)(Pay[p + 3] >> 18);
        float a0 = x[(size_t)c0 * 64 + d], a1 = x[(size_t)c1 * 64 + d];
        float a2 = x[(size_t)c2 * 64 + d], a3 = x[(size_t)c3 * 64 + d];
        acc += (a0 + a1) + (a2 + a3);
    }
    for (; p < p1; ++p)
        acc += x[(size_t)(Pay[p] >> 18) * 64 + d];
    ws[OF_MEAN + (size_t)sign * NF + (size_t)i * 64 + d] = sane(acc / (float)(p1 - p0 + 1));
}

__device__ __forceinline__ void pool_role(int b, const void* __restrict__ efp,
                                          const void* __restrict__ efn,
                                          const uint32_t* __restrict__ iws,
                                          uint32_t fB, float* __restrict__ ws){
    int wid = threadIdx.x >> 6, lane = threadIdx.x & 63;
    int gw = b * 4 + wid;
    int g = gw / N, i = gw - g * N;
    const void* ef = (g < 2) ? efp : efn;
    const uint32_t* P   = iws + OI_PTR + (size_t)g * (N + 1);
    const uint32_t* Pay = iws + OI_PAY + (size_t)g * Eg;
    int f = lane & 31, h = lane >> 5;
    float m = 0.f;
    uint32_t p0 = P[i], p1 = P[i + 1];
    if (p1 > (uint32_t)Eg) p1 = Eg;
    if (p0 > p1) p0 = p1;
    uint32_t p = p0 + h;
    if (fB){
        const float* E = (const float*)ef;
        for (; p + 2 < p1; p += 4){
            uint32_t e0 = Pay[p] & 0x3FFFFu, e1 = Pay[p + 2] & 0x3FFFFu;
            m = fmaxf(m, fmaxf(E[(size_t)e0 * 32 + f], E[(size_t)e1 * 32 + f]));
        }
        for (; p < p1; p += 2)
            m = fmaxf(m, E[(size_t)(Pay[p] & 0x3FFFFu) * 32 + f]);
    } else {
        const bf* E = (const bf*)ef;
        for (; p + 2 < p1; p += 4){
            uint32_t e0 = Pay[p] & 0x3FFFFu, e1 = Pay[p + 2] & 0x3FFFFu;
            m = fmaxf(m, fmaxf(b2f(E[(size_t)e0 * 32 + f]), b2f(E[(size_t)e1 * 32 + f])));
        }
        for (; p < p1; p += 2)
            m = fmaxf(m, b2f(E[(size_t)(Pay[p] & 0x3FFFFu) * 32 + f]));
    }
    m = fmaxf(m, __shfl_xor(m, 32, 64));
    m = sane(m);
    float ss = m * m;
    ss += __shfl_xor(ss, 16, 64); ss += __shfl_xor(ss, 8, 64);
    ss += __shfl_xor(ss, 4, 64);  ss += __shfl_xor(ss, 2, 64);
    ss += __shfl_xor(ss, 1, 64);
    float r = m / fmaxf(sqrtf(ss), 1e-12f);
    if (lane < 32) ws[OF_POOL + ((size_t)g * N + i) * 32 + f] = sane(r);
}

__device__ __forceinline__ void corr_role(int b, const uint32_t* __restrict__ iws,
                                          const float* __restrict__ ws_ro,
                                          float* __restrict__ O, float* __restrict__ Lg){
    int wid = threadIdx.x >> 6, d = threadIdx.x & 63;
    int gw = b * 4 + wid;
    int sg = gw >= N;
    int i = gw - sg * N;
    const bf* Qb = (const bf*)(ws_ro + OF_QKVB) + (size_t)(sg * 3) * NF;
    const bf* Kb = Qb + NF;
    const bf* Vb = Kb + NF;
    const int csr = sg ? 2 : 0;
    const uint32_t* Pp  = iws + OI_PTR + (size_t)csr * (N + 1);
    const uint32_t* Pay = iws + OI_PAY + (size_t)csr * Eg;
    float q = b2f(Qb[(size_t)i * 64 + d]);
    float corrO = 0.f, corrL = 0.f;
    uint32_t p0 = Pp[i], p1 = Pp[i + 1];
    if (p1 > (uint32_t)Eg) p1 = Eg;
    if (p0 > p1) p0 = p1;
    constexpr float C = 0.63212055882f;      // 1 - 1/e
    uint32_t p = p0;
    for (; p + 2 <= p1; p += 2){
        int c0 = (int)(Pay[p] >> 18), c1 = (int)(Pay[p + 1] >> 18);
        float s0 = q * b2f(Kb[(size_t)c0 * 64 + d]);
        float s1 = q * b2f(Kb[(size_t)c1 * 64 + d]);
        s0 += __shfl_xor(s0, 32, 64); s1 += __shfl_xor(s1, 32, 64);
        s0 += __shfl_xor(s0, 16, 64); s1 += __shfl_xor(s1, 16, 64);
        s0 += __shfl_xor(s0, 8, 64);  s1 += __shfl_xor(s1, 8, 64);
        s0 += __shfl_xor(s0, 4, 64);  s1 += __shfl_xor(s1, 4, 64);
        s0 += __shfl_xor(s0, 2, 64);  s1 += __shfl_xor(s1, 2, 64);
        s0 += __shfl_xor(s0, 1, 64);  s1 += __shfl_xor(s1, 1, 64);
        float f0 = C * __expf(s0 + 1.0f);
        float f1 = C * __expf(s1 + 1.0f);
        corrO += f0 * b2f(Vb[(size_t)c0 * 64 + d]) + f1 * b2f(Vb[(size_t)c1 * 64 + d]);
        corrL += f0 + f1;
    }
    for (int extra = 0; extra < 2; ++extra){
        int c;
        if (extra == 0){ if (p >= p1) continue; c = (int)(Pay[p] >> 18); }
        else c = i;                              // diagonal
        float s = q * b2f(Kb[(size_t)c * 64 + d]);
        s += __shfl_xor(s, 32, 64); s += __shfl_xor(s, 16, 64); s += __shfl_xor(s, 8, 64);
        s += __shfl_xor(s, 4, 64);  s += __shfl_xor(s, 2, 64);  s += __shfl_xor(s, 1, 64);
        float f = C * __expf(s + 1.0f);
        corrO += f * b2f(Vb[(size_t)c * 64 + d]);
        corrL += f;
    }
    atomicAdd(&O[((size_t)sg * N + i) * 64 + d], -corrO);
    if (d == 0) atomicAdd(&Lg[(size_t)sg * N + i], -corrL);
}

__global__ void mega_kernel(const void* __restrict__ efp, const void* __restrict__ efn,
                            const uint32_t* __restrict__ iws,
                            const uint32_t* __restrict__ flags, float* __restrict__ ws){
    int b = blockIdx.x;
    if (b < 3072)       mean_role(b, iws, ws, ws);
    else if (b < 9216)  pool_role(b - 3072, efp, efn, iws, flags[1], ws);
    else                corr_role(b - 9216, iws, ws, ws + OF_O, ws + OF_L);
}

// ---- K8: fused epilogue ----
__global__ void final_kernel(const uint32_t* __restrict__ flags,
                             const float* __restrict__ ws, void* __restrict__ outv){
    uint32_t fA = flags[0];
    int wid = threadIdx.x >> 6, c = threadIdx.x & 63;
    int i = blockIdx.x * 4 + wid;
    __shared__ float feat[4][384];
    __shared__ float onrm[4][64];
    for (int s = 0; s < 2; ++s){
        float osum = ws[OF_O + ((size_t)s * N + i) * 64 + c];
        float lsum = ws[OF_L + (size_t)s * N + i];
        onrm[wid][c] = sane(osum / fmaxf(lsum, 1e-20f));
        __syncthreads();
        const float* Wo = ws + OF_WO + (size_t)s * 4096;
        float attn = ws[OF_BO + s * 64 + c];
        #pragma unroll 8
        for (int d = 0; d < 64; ++d) attn += onrm[wid][d] * Wo[d * 64 + c];
        feat[wid][s * 64 + c] = sane(ws[OF_MEAN + (size_t)s * NF + (size_t)i * 64 + c] + attn);
        __syncthreads();
    }
    feat[wid][128 + c] = ws[OF_XF + (size_t)i * 64 + c];
    feat[wid][192 + c] = ws[OF_XF + NF + (size_t)i * 64 + c];
    {
        int g0 = c >> 5, f = c & 31;
        feat[wid][256 + c] = ws[OF_POOL + ((size_t)g0 * N + i) * 32 + f];
        feat[wid][320 + c] = ws[OF_POOL + ((size_t)(2 + g0) * N + i) * 32 + f];
    }
    __syncthreads();
    float acc = ws[OF_BF + c];
    #pragma unroll 8
    for (int k = 0; k < 384; ++k) acc += feat[wid][k] * ws[OF_WF + (size_t)k * 64 + c];
    acc = sane(acc);
    float ss = acc * acc;
    ss += __shfl_xor(ss, 32, 64); ss += __shfl_xor(ss, 16, 64); ss += __shfl_xor(ss, 8, 64);
    ss += __shfl_xor(ss, 4, 64);  ss += __shfl_xor(ss, 2, 64);  ss += __shfl_xor(ss, 1, 64);
    float r = acc / fmaxf(sqrtf(ss), 1e-12f);
    if (fA) ((float*)outv)[(size_t)i * 64 + c] = r;
    else    ((bf*)outv)[(size_t)i * 64 + c] = __float2bfloat16(r);
}

extern "C" void kernel_launch(void* const* d_in, const int* in_sizes, int n_in,
                              void* d_out, int out_size, void* d_ws, size_t ws_size,
                              hipStream_t stream){
    const int* eip = (const int*)d_in[2];
    const int* ein = (const int*)d_in[3];

    float* ws = (float*)d_ws;
    uint32_t* iws = (uint32_t*)(ws + F_TOTAL);
    uint32_t* flags = iws + OI_FLAG;
    float* O  = ws + OF_O;
    float* Lg = ws + OF_L;

    prep0_kernel<<<dim3(3217), 256, 0, stream>>>(d_in[0], d_in[4], d_in[6], d_in[8],
                                                 O, iws + OI_CNT, flags);
    prep1_kernel<<<dim3(4067), 256, 0, stream>>>(
        d_in[0], d_in[1],
        d_in[8],  d_in[10], d_in[12], d_in[16], d_in[18], d_in[20],
        d_in[9],  d_in[11], d_in[13], d_in[17], d_in[19], d_in[21],
        d_in[14], d_in[15], d_in[22], d_in[23],
        d_in[6],  d_in[7],
        eip, ein, flags, ws, iws);
    scan_kernel<<<4, 256, 0, stream>>>(iws);
    fillqkv_kernel<<<dim3(768 + 9216), 256, 0, stream>>>(eip, ein, iws, ws);
    transpose_kernel<<<dim3(192), 256, 0, stream>>>(ws);
    attn_dense_kernel<<<dim3(N / 64, 8, 2), 256, 0, stream>>>(ws, O, Lg);
    mega_kernel<<<dim3(12288), 256, 0, stream>>>(d_in[4], d_in[5], iws, flags, ws);
    final_kernel<<<dim3(N / 4), 256, 0, stream>>>(flags, ws, d_out);
}

// Round 8
// 490.363 us; speedup vs baseline: 1.1386x; 1.1386x over previous
//
#include <hip/hip_runtime.h>
#include <hip/hip_bf16.h>
#include <stdint.h>

typedef __hip_bfloat16 bf;
typedef __attribute__((ext_vector_type(8))) short short8;
typedef __attribute__((ext_vector_type(4))) float float4v;
__device__ __forceinline__ float b2f(bf x){ return __bfloat162float(x); }
__device__ __forceinline__ float sane(float x){ return fminf(fmaxf(x, -1e6f), 1e6f); }
__device__ __forceinline__ short f2b(float f){
    uint32_t u = __float_as_uint(f);
    u += 0x7fffu + ((u >> 16) & 1u);
    return (short)(u >> 16);
}

// Problem constants
constexpr int N   = 6144;          // NOT a power of two (3*2^11)!
constexpr int D   = 64;
constexpr int FE  = 32;
constexpr int Eg  = 196608;        // < 2^18 -> edge id packs in 18 bits
constexpr size_t NF = (size_t)N * D;

__device__ __forceinline__ int clampi(int v){ return v < 0 ? 0 : (v >= N ? N - 1 : v); }
__device__ __forceinline__ float ldf(const void* p, size_t i, uint32_t isf32){
    return isf32 ? ((const float*)p)[i] : b2f(((const bf*)p)[i]);
}

// ---- float workspace layout (floats) ----  ~17.6 MB
constexpr size_t OF_O    = 0;                           // [2][N][D] attn numerator (atomic)
constexpr size_t OF_L    = OF_O + 2*NF;                 // [2][N]
constexpr size_t OF_MEAN = OF_L + 2*(size_t)N;          // [2][N][D]
constexpr size_t OF_POOL = OF_MEAN + 2*NF;              // [4][N][FE]
constexpr size_t OF_QKVB = OF_POOL + (size_t)4*N*FE;    // bf16 [2][3][N][D] (Q pre-scaled)
constexpr size_t OF_XF   = OF_QKVB + 3*NF;              // [2][N][D] f32 staged x1,x2
constexpr size_t OF_WA   = OF_XF + 2*NF;                // [6][64][64]
constexpr size_t OF_BA   = OF_WA + 24576;               // [6][64]
constexpr size_t OF_WO   = OF_BA + 384;                 // [2][64][64]
constexpr size_t OF_BO   = OF_WO + 8192;                // [2][64]
constexpr size_t OF_WF   = OF_BO + 128;                 // [384][64]
constexpr size_t OF_BF   = OF_WF + 24576;               // [64]
constexpr size_t F_TOTAL = OF_BF + 64;
// ---- u32 workspace (words, after float region) ----  ~3.44 MB
constexpr size_t OI_CNT  = 0;                           // [4][N]
constexpr size_t OI_PTR  = OI_CNT + 4*(size_t)N;        // [4][N+1]
constexpr size_t OI_CUR  = OI_PTR + 4*(size_t)(N+1);    // [4][N]
constexpr size_t OI_PAY  = OI_CUR + 4*(size_t)N;        // [4][Eg]  e | (other<<18)
constexpr size_t OI_FLAG = OI_PAY + 4*(size_t)Eg;       // [4] dtype flags

constexpr int NZF = (int)(2*NF + 2*(size_t)N);          // O + L floats to zero

// ---- K1: zero O/L + zero CSR counts + dtype sniff ----
__global__ void prep0_kernel(const void* xA, const void* xB, const void* xC, const void* xD,
                             float* __restrict__ fz, uint32_t* __restrict__ uz,
                             uint32_t* __restrict__ flags){
    int b = blockIdx.x, t = threadIdx.x;
    if (b < 3120){
        int i = b * 256 + t;
        if (i < NZF) fz[i] = 0.f;
    } else if (b < 3216){
        int i = (b - 3120) * 256 + t;
        if (i < 24576) uz[i] = 0u;
    } else {
        __shared__ float red[256];
        const void* ps[4] = {xA, xB, xC, xD};
        for (int k = 0; k < 4; ++k){
            const bf* p = (const bf*)ps[k];
            float m = 0.f;
            for (int i = t; i < 1024; i += 256){
                float v = fabsf(b2f(p[i]));
                if (!(v <= 1e9f)) v = 1e9f;
                m = fmaxf(m, v);
            }
            red[t] = m; __syncthreads();
            for (int off = 128; off; off >>= 1){
                if (t < off) red[t] = fmaxf(red[t], red[t + off]);
                __syncthreads();
            }
            if (t == 0) flags[k] = (red[0] > 100.f) ? 1u : 0u;
            __syncthreads();
        }
    }
}

// ---- K2: convert (x, attn W/b, final W/b) + CSR degree counts ----
__global__ void prep1_kernel(const void* x1, const void* x2,
                             const void* W0, const void* W1, const void* W2,
                             const void* W3, const void* W4, const void* W5,
                             const void* B0, const void* B1, const void* B2,
                             const void* B3, const void* B4, const void* B5,
                             const void* Wop, const void* bop,
                             const void* Won, const void* bon,
                             const void* wgt, const void* bia,
                             const int* __restrict__ eip, const int* __restrict__ ein,
                             const uint32_t* __restrict__ flags,
                             float* __restrict__ ws, uint32_t* __restrict__ iws){
    int b = blockIdx.x, t = threadIdx.x;
    if (b < 3072){
        size_t idx = (size_t)b * 256 + t;
        uint32_t fA = flags[0];
        float v = (idx < NF) ? ldf(x1, idx, fA) : ldf(x2, idx - NF, fA);
        ws[OF_XF + idx] = sane(v);
    } else if (b < 3202){
        size_t idx = (size_t)(b - 3072) * 256 + t;
        if (idx >= 33280) return;
        uint32_t fD = flags[3];
        float v;
        if (idx < 24576){
            int m = (int)(idx >> 12), sub = (int)(idx & 4095);
            const void* W = (m==0)?W0:(m==1)?W1:(m==2)?W2:(m==3)?W3:(m==4)?W4:W5;
            v = ldf(W, sub, fD);
        } else if (idx < 24960){
            int m = (int)((idx - 24576) >> 6), sub = (int)(idx & 63);
            const void* B = (m==0)?B0:(m==1)?B1:(m==2)?B2:(m==3)?B3:(m==4)?B4:B5;
            v = ldf(B, sub, fD);
        } else if (idx < 33152){
            int k = (int)((idx - 24960) >> 12), sub = (int)(idx & 4095);
            v = ldf(k ? Won : Wop, sub, fD);
        } else {
            int k = (int)((idx - 33152) >> 6), sub = (int)(idx & 63);
            v = ldf(k ? bon : bop, sub, fD);
        }
        ws[OF_WA + idx] = sane(v);
    } else if (b < 3299){
        size_t idx = (size_t)(b - 3202) * 256 + t;
        if (idx >= 24640) return;
        uint32_t fC = flags[2];
        float v = (idx < 24576) ? ldf(wgt, idx, fC) : ldf(bia, idx - 24576, fC);
        ws[OF_WF + idx] = sane(v);
    } else {
        int e = (b - 3299) * 256 + t;
        if (e >= Eg) return;
        uint32_t* cnt = iws + OI_CNT;
        atomicAdd(&cnt[0 * N + clampi(eip[e])],      1u);
        atomicAdd(&cnt[1 * N + clampi(eip[Eg + e])], 1u);
        atomicAdd(&cnt[2 * N + clampi(ein[e])],      1u);
        atomicAdd(&cnt[3 * N + clampi(ein[Eg + e])], 1u);
    }
}

__global__ void scan_kernel(uint32_t* __restrict__ iws){
    int b = blockIdx.x, t = threadIdx.x;
    const uint32_t* c = iws + OI_CNT + (size_t)b * N;
    uint32_t* P  = iws + OI_PTR + (size_t)b * (N + 1);
    uint32_t* Cu = iws + OI_CUR + (size_t)b * N;
    constexpr int K = N / 256;
    int base = t * K;
    uint32_t s = 0;
    for (int k = 0; k < K; ++k) s += c[base + k];
    __shared__ uint32_t sums[256];
    sums[t] = s; __syncthreads();
    for (int off = 1; off < 256; off <<= 1){
        uint32_t v = (t >= off) ? sums[t - off] : 0u;
        __syncthreads();
        sums[t] += v;
        __syncthreads();
    }
    uint32_t run = (t == 0) ? 0u : sums[t - 1];
    for (int k = 0; k < K; ++k){ P[base + k] = run; Cu[base + k] = run; run += c[base + k]; }
    if (t == 255) P[N] = run;
}

// ---- K4: CSR fill + QKV projections ----
__global__ void fillqkv_kernel(const int* __restrict__ eip, const int* __restrict__ ein,
                               uint32_t* __restrict__ iws, float* __restrict__ ws){
    int b = blockIdx.x;
    if (b < 768){
        int e = b * 256 + threadIdx.x;
        if (e >= Eg) return;
        uint32_t* Cu  = iws + OI_CUR;
        uint32_t* Pay = iws + OI_PAY;
        int rp = clampi(eip[e]), cp = clampi(eip[Eg + e]);
        int rn = clampi(ein[e]), cn = clampi(ein[Eg + e]);
        uint32_t p;
        p = atomicAdd(&Cu[0 * N + rp], 1u); if (p < Eg) Pay[0 * (size_t)Eg + p] = (uint32_t)e | ((uint32_t)cp << 18);
        p = atomicAdd(&Cu[1 * N + cp], 1u); if (p < Eg) Pay[1 * (size_t)Eg + p] = (uint32_t)e | ((uint32_t)rp << 18);
        p = atomicAdd(&Cu[2 * N + rn], 1u); if (p < Eg) Pay[2 * (size_t)Eg + p] = (uint32_t)e | ((uint32_t)cn << 18);
        p = atomicAdd(&Cu[3 * N + cn], 1u); if (p < Eg) Pay[3 * (size_t)Eg + p] = (uint32_t)e | ((uint32_t)rn << 18);
    } else {
        int bb = b - 768;
        int m = bb / 1536, ib = bb - m * 1536;
        int wid = threadIdx.x >> 6, lane = threadIdx.x & 63;
        int i = ib * 4 + wid;
        const float* x = ws + OF_XF + (m < 3 ? 0 : NF) + (size_t)i * 64;
        const float* W = ws + OF_WA + (size_t)m * 4096;
        float xreg = x[lane];
        float acc = ws[OF_BA + m * 64 + lane];
        #pragma unroll 16
        for (int d = 0; d < 64; ++d)
            acc += __shfl(xreg, d, 64) * W[d * 64 + lane];
        acc = sane(acc);
        if (m == 0 || m == 3) acc *= 0.125f;   // fold softmax scale into Q
        bf* qkvb = (bf*)(ws + OF_QKVB);
        qkvb[(size_t)m * NF + (size_t)i * 64 + lane] = __float2bfloat16(acc);
    }
}

// ---- K5: dense unmasked attention, LDS-staged, conflict-free layout ----
// Pitch 66 halfs (33 dwords, odd -> row r starts at bank r); 16B granules stored
// interleaved [g0 g4 g1 g5 g2 g6 g3 g7] so fragment reads hit bank m16+8*quad+d
// (exactly 2 lanes/bank = free). P: pitch 33 dwords, same granule interleave.
__global__ void __launch_bounds__(256, 4)
attn_dense_kernel(const float* __restrict__ ws_ro, float* __restrict__ O,
                  float* __restrict__ Lg){
    __shared__ __align__(16) short Kl[64 * 66];    // [col][k granule-interleaved]
    __shared__ __align__(16) short Vl[64 * 66];    // [dim][col granule-interleaved]
    __shared__ __align__(16) float Pl[4][16 * 33]; // per-wave P round-trip

    int tid = threadIdx.x, lane = tid & 63, wv = tid >> 6;
    int m16 = lane & 15, quad = lane >> 4;
    int rt = blockIdx.x, cs = blockIdx.y, sg = blockIdx.z;
    const bf* qkvb = (const bf*)(ws_ro + OF_QKVB);
    const bf* Qb = qkvb + (size_t)(sg * 3) * NF;
    const bf* Kb = Qb + NF;
    const bf* Vb = Kb + NF;

    int rowbase = rt * 64 + wv * 16;
    short8 Qf0 = *(const short8*)(Qb + (size_t)(rowbase + m16) * 64 + quad * 8);
    short8 Qf1 = *(const short8*)(Qb + (size_t)(rowbase + m16) * 64 + 32 + quad * 8);

    float4v Oc[4];
    #pragma unroll
    for (int t = 0; t < 4; ++t) Oc[t] = (float4v){0.f, 0.f, 0.f, 0.f};
    float l = 0.f;

    int scol = tid & 63, sgrp = tid >> 6;
    // staging write positions (granule-interleaved)
    int g0 = 2 * sgrp, g1 = g0 + 1;
    int posK0 = (g0 & 3) * 16 + (g0 >> 2) * 8;
    int posK1 = (g1 & 3) * 16 + (g1 >> 2) * 8;
    int vg = scol >> 3;
    int vcol = (vg & 3) * 16 + (vg >> 2) * 8 + (scol & 7);
    // P read positions (granules 2q, 2q+1 of 4 dwords)
    int posA = ((2 * quad) & 3) * 8 + ((2 * quad) >> 2) * 4;
    int posB = ((2 * quad + 1) & 3) * 8 + ((2 * quad + 1) >> 2) * 4;

    int c0 = cs * (N / 8);
    // prefetch tile 0 into registers
    const short* ksrc = (const short*)(Kb + (size_t)(c0 + scol) * 64 + sgrp * 16);
    short8 ka = *(const short8*)ksrc, kc = *(const short8*)(ksrc + 8);
    const short* vsrc = (const short*)(Vb + (size_t)(c0 + scol) * 64 + sgrp * 16);
    short8 va = *(const short8*)vsrc, vc = *(const short8*)(vsrc + 8);

    for (int cb = c0; cb < c0 + N / 8; cb += 64){
        // write staged regs to LDS (K row-major granules; V transposed scatter)
        *(short8*)(&Kl[scol * 66 + posK0]) = ka;
        *(short8*)(&Kl[scol * 66 + posK1]) = kc;
        #pragma unroll
        for (int j = 0; j < 8; ++j) Vl[(sgrp * 16 + j) * 66 + vcol] = va[j];
        #pragma unroll
        for (int j = 0; j < 8; ++j) Vl[(sgrp * 16 + 8 + j) * 66 + vcol] = vc[j];
        // issue next tile's global loads (overlap with compute)
        if (cb + 64 < c0 + N / 8){
            const short* kn = (const short*)(Kb + (size_t)(cb + 64 + scol) * 64 + sgrp * 16);
            ka = *(const short8*)kn; kc = *(const short8*)(kn + 8);
            const short* vn = (const short*)(Vb + (size_t)(cb + 64 + scol) * 64 + sgrp * 16);
            va = *(const short8*)vn; vc = *(const short8*)(vn + 8);
        }
        __syncthreads();

        float* Pw = Pl[wv];
        #pragma unroll
        for (int kg = 0; kg < 2; ++kg){
            #pragma unroll
            for (int ct = 0; ct < 2; ++ct){
                int colt = kg * 32 + ct * 16;
                short8 A0 = *(const short8*)(&Kl[(colt + m16) * 66 + quad * 16]);
                short8 A1 = *(const short8*)(&Kl[(colt + m16) * 66 + quad * 16 + 8]);
                float4v s = __builtin_amdgcn_mfma_f32_16x16x32_bf16(
                                A0, Qf0, (float4v){0.f,0.f,0.f,0.f}, 0, 0, 0);
                s = __builtin_amdgcn_mfma_f32_16x16x32_bf16(A1, Qf1, s, 0, 0, 0);
                float4v pv;
                #pragma unroll
                for (int r = 0; r < 4; ++r){
                    pv[r] = __expf(s[r] + 1.0f);
                    l += pv[r];
                }
                *(float4v*)(&Pw[m16 * 33 + quad * 8 + ct * 4]) = pv;
            }
            asm volatile("s_waitcnt lgkmcnt(0)" ::: "memory");
            float4v pa = *(const float4v*)(&Pw[m16 * 33 + posA]);
            float4v pb = *(const float4v*)(&Pw[m16 * 33 + posB]);
            short8 Pf;
            #pragma unroll
            for (int j = 0; j < 4; ++j){ Pf[j] = f2b(pa[j]); Pf[4 + j] = f2b(pb[j]); }
            #pragma unroll
            for (int dt = 0; dt < 4; ++dt){
                short8 Va = *(const short8*)(&Vl[(dt * 16 + m16) * 66 + quad * 16 + kg * 8]);
                Oc[dt] = __builtin_amdgcn_mfma_f32_16x16x32_bf16(Va, Pf, Oc[dt], 0, 0, 0);
            }
        }
        __syncthreads();
    }
    l += __shfl_xor(l, 16, 64);
    l += __shfl_xor(l, 32, 64);
    if (quad == 0) atomicAdd(&Lg[(size_t)sg * N + rowbase + m16], l);
    float* Op = O + ((size_t)sg * N + rowbase + m16) * 64;
    #pragma unroll
    for (int dt = 0; dt < 4; ++dt)
        #pragma unroll
        for (int r = 0; r < 4; ++r)
            atomicAdd(&Op[dt * 16 + quad * 4 + r], Oc[dt][r]);
}

// ---- mega kernel roles (verified round 6) ----
__device__ __forceinline__ void mean_role(int b, const uint32_t* __restrict__ iws,
                                          const float* __restrict__ ws_ro, float* __restrict__ ws){
    int wid = threadIdx.x >> 6, d = threadIdx.x & 63;
    int gw = b * 4 + wid;
    int sign = gw >= N;
    int i = gw - sign * N;
    const float* x = ws_ro + OF_XF + (size_t)sign * NF;
    int csr = sign ? 2 : 0;
    const uint32_t* P   = iws + OI_PTR + (size_t)csr * (N + 1);
    const uint32_t* Pay = iws + OI_PAY + (size_t)csr * Eg;
    float acc = x[(size_t)i * 64 + d];
    uint32_t p0 = P[i], p1 = P[i + 1];
    if (p1 > (uint32_t)Eg) p1 = Eg;
    if (p0 > p1) p0 = p1;
    uint32_t p = p0;
    for (; p + 4 <= p1; p += 4){
        int c0 = (int)(Pay[p]     >> 18);
        int c1 = (int)(Pay[p + 1] >> 18);
        int c2 = (int)(Pay[p + 2] >> 18);
        int c3 = (int)(Pay[p + 3] >> 18);
        float a0 = x[(size_t)c0 * 64 + d], a1 = x[(size_t)c1 * 64 + d];
        float a2 = x[(size_t)c2 * 64 + d], a3 = x[(size_t)c3 * 64 + d];
        acc += (a0 + a1) + (a2 + a3);
    }
    for (; p < p1; ++p)
        acc += x[(size_t)(Pay[p] >> 18) * 64 + d];
    ws[OF_MEAN + (size_t)sign * NF + (size_t)i * 64 + d] = sane(acc / (float)(p1 - p0 + 1));
}

__device__ __forceinline__ void pool_role(int b, const void* __restrict__ efp,
                                          const void* __restrict__ efn,
                                          const uint32_t* __restrict__ iws,
                                          uint32_t fB, float* __restrict__ ws){
    int wid = threadIdx.x >> 6, lane = threadIdx.x & 63;
    int gw = b * 4 + wid;
    int g = gw / N, i = gw - g * N;
    const void* ef = (g < 2) ? efp : efn;
    const uint32_t* P   = iws + OI_PTR + (size_t)g * (N + 1);
    const uint32_t* Pay = iws + OI_PAY + (size_t)g * Eg;
    int f = lane & 31, h = lane >> 5;
    float m = 0.f;
    uint32_t p0 = P[i], p1 = P[i + 1];
    if (p1 > (uint32_t)Eg) p1 = Eg;
    if (p0 > p1) p0 = p1;
    uint32_t p = p0 + h;
    if (fB){
        const float* E = (const float*)ef;
        for (; p + 2 < p1; p += 4){
            uint32_t e0 = Pay[p] & 0x3FFFFu, e1 = Pay[p + 2] & 0x3FFFFu;
            m = fmaxf(m, fmaxf(E[(size_t)e0 * 32 + f], E[(size_t)e1 * 32 + f]));
        }
        for (; p < p1; p += 2)
            m = fmaxf(m, E[(size_t)(Pay[p] & 0x3FFFFu) * 32 + f]);
    } else {
        const bf* E = (const bf*)ef;
        for (; p + 2 < p1; p += 4){
            uint32_t e0 = Pay[p] & 0x3FFFFu, e1 = Pay[p + 2] & 0x3FFFFu;
            m = fmaxf(m, fmaxf(b2f(E[(size_t)e0 * 32 + f]), b2f(E[(size_t)e1 * 32 + f])));
        }
        for (; p < p1; p += 2)
            m = fmaxf(m, b2f(E[(size_t)(Pay[p] & 0x3FFFFu) * 32 + f]));
    }
    m = fmaxf(m, __shfl_xor(m, 32, 64));
    m = sane(m);
    float ss = m * m;
    ss += __shfl_xor(ss, 16, 64); ss += __shfl_xor(ss, 8, 64);
    ss += __shfl_xor(ss, 4, 64);  ss += __shfl_xor(ss, 2, 64);
    ss += __shfl_xor(ss, 1, 64);
    float r = m / fmaxf(sqrtf(ss), 1e-12f);
    if (lane < 32) ws[OF_POOL + ((size_t)g * N + i) * 32 + f] = sane(r);
}

__device__ __forceinline__ void corr_role(int b, const uint32_t* __restrict__ iws,
                                          const float* __restrict__ ws_ro,
                                          float* __restrict__ O, float* __restrict__ Lg){
    int wid = threadIdx.x >> 6, d = threadIdx.x & 63;
    int gw = b * 4 + wid;
    int sg = gw >= N;
    int i = gw - sg * N;
    const bf* Qb = (const bf*)(ws_ro + OF_QKVB) + (size_t)(sg * 3) * NF;
    const bf* Kb = Qb + NF;
    const bf* Vb = Kb + NF;
    const int csr = sg ? 2 : 0;
    const uint32_t* Pp  = iws + OI_PTR + (size_t)csr * (N + 1);
    const uint32_t* Pay = iws + OI_PAY + (size_t)csr * Eg;
    float q = b2f(Qb[(size_t)i * 64 + d]);
    float corrO = 0.f, corrL = 0.f;
    uint32_t p0 = Pp[i], p1 = Pp[i + 1];
    if (p1 > (uint32_t)Eg) p1 = Eg;
    if (p0 > p1) p0 = p1;
    constexpr float C = 0.63212055882f;      // 1 - 1/e
    uint32_t p = p0;
    for (; p + 2 <= p1; p += 2){
        int c0 = (int)(Pay[p] >> 18), c1 = (int)(Pay[p + 1] >> 18);
        float s0 = q * b2f(Kb[(size_t)c0 * 64 + d]);
        float s1 = q * b2f(Kb[(size_t)c1 * 64 + d]);
        s0 += __shfl_xor(s0, 32, 64); s1 += __shfl_xor(s1, 32, 64);
        s0 += __shfl_xor(s0, 16, 64); s1 += __shfl_xor(s1, 16, 64);
        s0 += __shfl_xor(s0, 8, 64);  s1 += __shfl_xor(s1, 8, 64);
        s0 += __shfl_xor(s0, 4, 64);  s1 += __shfl_xor(s1, 4, 64);
        s0 += __shfl_xor(s0, 2, 64);  s1 += __shfl_xor(s1, 2, 64);
        s0 += __shfl_xor(s0, 1, 64);  s1 += __shfl_xor(s1, 1, 64);
        float f0 = C * __expf(s0 + 1.0f);
        float f1 = C * __expf(s1 + 1.0f);
        corrO += f0 * b2f(Vb[(size_t)c0 * 64 + d]) + f1 * b2f(Vb[(size_t)c1 * 64 + d]);
        corrL += f0 + f1;
    }
    for (int extra = 0; extra < 2; ++extra){
        int c;
        if (extra == 0){ if (p >= p1) continue; c = (int)(Pay[p] >> 18); }
        else c = i;                              // diagonal
        float s = q * b2f(Kb[(size_t)c * 64 + d]);
        s += __shfl_xor(s, 32, 64); s += __shfl_xor(s, 16, 64); s += __shfl_xor(s, 8, 64);
        s += __shfl_xor(s, 4, 64);  s += __shfl_xor(s, 2, 64);  s += __shfl_xor(s, 1, 64);
        float f = C * __expf(s + 1.0f);
        corrO += f * b2f(Vb[(size_t)c * 64 + d]);
        corrL += f;
    }
    atomicAdd(&O[((size_t)sg * N + i) * 64 + d], -corrO);
    if (d == 0) atomicAdd(&Lg[(size_t)sg * N + i], -corrL);
}

__global__ void mega_kernel(const void* __restrict__ efp, const void* __restrict__ efn,
                            const uint32_t* __restrict__ iws,
                            const uint32_t* __restrict__ flags, float* __restrict__ ws){
    int b = blockIdx.x;
    if (b < 3072)       mean_role(b, iws, ws, ws);
    else if (b < 9216)  pool_role(b - 3072, efp, efn, iws, flags[1], ws);
    else                corr_role(b - 9216, iws, ws, ws + OF_O, ws + OF_L);
}

// ---- K7: fused epilogue ----
__global__ void final_kernel(const uint32_t* __restrict__ flags,
                             const float* __restrict__ ws, void* __restrict__ outv){
    uint32_t fA = flags[0];
    int wid = threadIdx.x >> 6, c = threadIdx.x & 63;
    int i = blockIdx.x * 4 + wid;
    __shared__ float feat[4][384];
    __shared__ float onrm[4][64];
    for (int s = 0; s < 2; ++s){
        float osum = ws[OF_O + ((size_t)s * N + i) * 64 + c];
        float lsum = ws[OF_L + (size_t)s * N + i];
        onrm[wid][c] = sane(osum / fmaxf(lsum, 1e-20f));
        __syncthreads();
        const float* Wo = ws + OF_WO + (size_t)s * 4096;
        float attn = ws[OF_BO + s * 64 + c];
        #pragma unroll 8
        for (int d = 0; d < 64; ++d) attn += onrm[wid][d] * Wo[d * 64 + c];
        feat[wid][s * 64 + c] = sane(ws[OF_MEAN + (size_t)s * NF + (size_t)i * 64 + c] + attn);
        __syncthreads();
    }
    feat[wid][128 + c] = ws[OF_XF + (size_t)i * 64 + c];
    feat[wid][192 + c] = ws[OF_XF + NF + (size_t)i * 64 + c];
    {
        int g0 = c >> 5, f = c & 31;
        feat[wid][256 + c] = ws[OF_POOL + ((size_t)g0 * N + i) * 32 + f];
        feat[wid][320 + c] = ws[OF_POOL + ((size_t)(2 + g0) * N + i) * 32 + f];
    }
    __syncthreads();
    float acc = ws[OF_BF + c];
    #pragma unroll 8
    for (int k = 0; k < 384; ++k) acc += feat[wid][k] * ws[OF_WF + (size_t)k * 64 + c];
    acc = sane(acc);
    float ss = acc * acc;
    ss += __shfl_xor(ss, 32, 64); ss += __shfl_xor(ss, 16, 64); ss += __shfl_xor(ss, 8, 64);
    ss += __shfl_xor(ss, 4, 64);  ss += __shfl_xor(ss, 2, 64);  ss += __shfl_xor(ss, 1, 64);
    float r = acc / fmaxf(sqrtf(ss), 1e-12f);
    if (fA) ((float*)outv)[(size_t)i * 64 + c] = r;
    else    ((bf*)outv)[(size_t)i * 64 + c] = __float2bfloat16(r);
}

extern "C" void kernel_launch(void* const* d_in, const int* in_sizes, int n_in,
                              void* d_out, int out_size, void* d_ws, size_t ws_size,
                              hipStream_t stream){
    const int* eip = (const int*)d_in[2];
    const int* ein = (const int*)d_in[3];

    float* ws = (float*)d_ws;
    uint32_t* iws = (uint32_t*)(ws + F_TOTAL);
    uint32_t* flags = iws + OI_FLAG;
    float* O  = ws + OF_O;
    float* Lg = ws + OF_L;

    prep0_kernel<<<dim3(3217), 256, 0, stream>>>(d_in[0], d_in[4], d_in[6], d_in[8],
                                                 O, iws + OI_CNT, flags);
    prep1_kernel<<<dim3(4067), 256, 0, stream>>>(
        d_in[0], d_in[1],
        d_in[8],  d_in[10], d_in[12], d_in[16], d_in[18], d_in[20],
        d_in[9],  d_in[11], d_in[13], d_in[17], d_in[19], d_in[21],
        d_in[14], d_in[15], d_in[22], d_in[23],
        d_in[6],  d_in[7],
        eip, ein, flags, ws, iws);
    scan_kernel<<<4, 256, 0, stream>>>(iws);
    fillqkv_kernel<<<dim3(768 + 9216), 256, 0, stream>>>(eip, ein, iws, ws);
    attn_dense_kernel<<<dim3(N / 64, 8, 2), 256, 0, stream>>>(ws, O, Lg);
    mega_kernel<<<dim3(12288), 256, 0, stream>>>(d_in[4], d_in[5], iws, flags, ws);
    final_kernel<<<dim3(N / 4), 256, 0, stream>>>(flags, ws, d_out);
}

// Round 9
// 462.501 us; speedup vs baseline: 1.2072x; 1.0602x over previous
//
#include <hip/hip_runtime.h>
#include <hip/hip_bf16.h>
#include <stdint.h>

typedef __hip_bfloat16 bf;
typedef __attribute__((ext_vector_type(8))) short short8;
typedef __attribute__((ext_vector_type(4))) float float4v;
__device__ __forceinline__ float b2f(bf x){ return __bfloat162float(x); }
__device__ __forceinline__ float sane(float x){ return fminf(fmaxf(x, -1e6f), 1e6f); }
__device__ __forceinline__ short f2b(float f){
    uint32_t u = __float_as_uint(f);
    u += 0x7fffu + ((u >> 16) & 1u);
    return (short)(u >> 16);
}

// Problem constants
constexpr int N   = 6144;          // NOT a power of two (3*2^11)!
constexpr int D   = 64;
constexpr int FE  = 32;
constexpr int Eg  = 196608;        // < 2^18 -> edge id packs in 18 bits
constexpr size_t NF = (size_t)N * D;

__device__ __forceinline__ int clampi(int v){ return v < 0 ? 0 : (v >= N ? N - 1 : v); }
__device__ __forceinline__ float ldf(const void* p, size_t i, uint32_t isf32){
    return isf32 ? ((const float*)p)[i] : b2f(((const bf*)p)[i]);
}

// ---- float workspace layout (floats) ----  ~19.1 MB (round-7 footprint, proven)
constexpr size_t OF_O    = 0;                           // [2][N][D] attn numerator (atomic)
constexpr size_t OF_L    = OF_O + 2*NF;                 // [2][N]
constexpr size_t OF_MEAN = OF_L + 2*(size_t)N;          // [2][N][D]
constexpr size_t OF_POOL = OF_MEAN + 2*NF;              // [4][N][FE]
constexpr size_t OF_QKVB = OF_POOL + (size_t)4*N*FE;    // bf16 [2][3][N][D] (Q pre-scaled)
constexpr size_t OF_XF   = OF_QKVB + 3*NF;              // [2][N][D] f32 staged x1,x2
constexpr size_t OF_WA   = OF_XF + 2*NF;                // [6][64][64]
constexpr size_t OF_BA   = OF_WA + 24576;               // [6][64]
constexpr size_t OF_WO   = OF_BA + 384;                 // [2][64][64]
constexpr size_t OF_BO   = OF_WO + 8192;                // [2][64]
constexpr size_t OF_WF   = OF_BO + 128;                 // [384][64]
constexpr size_t OF_BF   = OF_WF + 24576;               // [64]
constexpr size_t OF_VT   = OF_BF + 64;                  // bf16 [2][64][N] = V^T slabs
constexpr size_t F_TOTAL = OF_VT + 393216;
// ---- u32 workspace (words, after float region) ----  ~3.44 MB
constexpr size_t OI_CNT  = 0;                           // [4][N]
constexpr size_t OI_PTR  = OI_CNT + 4*(size_t)N;        // [4][N+1]
constexpr size_t OI_CUR  = OI_PTR + 4*(size_t)(N+1);    // [4][N]
constexpr size_t OI_PAY  = OI_CUR + 4*(size_t)N;        // [4][Eg]  e | (other<<18)
constexpr size_t OI_FLAG = OI_PAY + 4*(size_t)Eg;       // [4] dtype flags

constexpr int NZF = (int)(2*NF + 2*(size_t)N);          // O + L floats to zero

// ---- K1: zero O/L + zero CSR counts + dtype sniff ----
__global__ void prep0_kernel(const void* xA, const void* xB, const void* xC, const void* xD,
                             float* __restrict__ fz, uint32_t* __restrict__ uz,
                             uint32_t* __restrict__ flags){
    int b = blockIdx.x, t = threadIdx.x;
    if (b < 3120){
        int i = b * 256 + t;
        if (i < NZF) fz[i] = 0.f;
    } else if (b < 3216){
        int i = (b - 3120) * 256 + t;
        if (i < 24576) uz[i] = 0u;
    } else {
        __shared__ float red[256];
        const void* ps[4] = {xA, xB, xC, xD};
        for (int k = 0; k < 4; ++k){
            const bf* p = (const bf*)ps[k];
            float m = 0.f;
            for (int i = t; i < 1024; i += 256){
                float v = fabsf(b2f(p[i]));
                if (!(v <= 1e9f)) v = 1e9f;
                m = fmaxf(m, v);
            }
            red[t] = m; __syncthreads();
            for (int off = 128; off; off >>= 1){
                if (t < off) red[t] = fmaxf(red[t], red[t + off]);
                __syncthreads();
            }
            if (t == 0) flags[k] = (red[0] > 100.f) ? 1u : 0u;
            __syncthreads();
        }
    }
}

// ---- K2: convert (x, attn W/b, final W/b) + CSR degree counts ----
__global__ void prep1_kernel(const void* x1, const void* x2,
                             const void* W0, const void* W1, const void* W2,
                             const void* W3, const void* W4, const void* W5,
                             const void* B0, const void* B1, const void* B2,
                             const void* B3, const void* B4, const void* B5,
                             const void* Wop, const void* bop,
                             const void* Won, const void* bon,
                             const void* wgt, const void* bia,
                             const int* __restrict__ eip, const int* __restrict__ ein,
                             const uint32_t* __restrict__ flags,
                             float* __restrict__ ws, uint32_t* __restrict__ iws){
    int b = blockIdx.x, t = threadIdx.x;
    if (b < 3072){
        size_t idx = (size_t)b * 256 + t;
        uint32_t fA = flags[0];
        float v = (idx < NF) ? ldf(x1, idx, fA) : ldf(x2, idx - NF, fA);
        ws[OF_XF + idx] = sane(v);
    } else if (b < 3202){
        size_t idx = (size_t)(b - 3072) * 256 + t;
        if (idx >= 33280) return;
        uint32_t fD = flags[3];
        float v;
        if (idx < 24576){
            int m = (int)(idx >> 12), sub = (int)(idx & 4095);
            const void* W = (m==0)?W0:(m==1)?W1:(m==2)?W2:(m==3)?W3:(m==4)?W4:W5;
            v = ldf(W, sub, fD);
        } else if (idx < 24960){
            int m = (int)((idx - 24576) >> 6), sub = (int)(idx & 63);
            const void* B = (m==0)?B0:(m==1)?B1:(m==2)?B2:(m==3)?B3:(m==4)?B4:B5;
            v = ldf(B, sub, fD);
        } else if (idx < 33152){
            int k = (int)((idx - 24960) >> 12), sub = (int)(idx & 4095);
            v = ldf(k ? Won : Wop, sub, fD);
        } else {
            int k = (int)((idx - 33152) >> 6), sub = (int)(idx & 63);
            v = ldf(k ? bon : bop, sub, fD);
        }
        ws[OF_WA + idx] = sane(v);
    } else if (b < 3299){
        size_t idx = (size_t)(b - 3202) * 256 + t;
        if (idx >= 24640) return;
        uint32_t fC = flags[2];
        float v = (idx < 24576) ? ldf(wgt, idx, fC) : ldf(bia, idx - 24576, fC);
        ws[OF_WF + idx] = sane(v);
    } else {
        int e = (b - 3299) * 256 + t;
        if (e >= Eg) return;
        uint32_t* cnt = iws + OI_CNT;
        atomicAdd(&cnt[0 * N + clampi(eip[e])],      1u);
        atomicAdd(&cnt[1 * N + clampi(eip[Eg + e])], 1u);
        atomicAdd(&cnt[2 * N + clampi(ein[e])],      1u);
        atomicAdd(&cnt[3 * N + clampi(ein[Eg + e])], 1u);
    }
}

__global__ void scan_kernel(uint32_t* __restrict__ iws){
    int b = blockIdx.x, t = threadIdx.x;
    const uint32_t* c = iws + OI_CNT + (size_t)b * N;
    uint32_t* P  = iws + OI_PTR + (size_t)b * (N + 1);
    uint32_t* Cu = iws + OI_CUR + (size_t)b * N;
    constexpr int K = N / 256;
    int base = t * K;
    uint32_t s = 0;
    for (int k = 0; k < K; ++k) s += c[base + k];
    __shared__ uint32_t sums[256];
    sums[t] = s; __syncthreads();
    for (int off = 1; off < 256; off <<= 1){
        uint32_t v = (t >= off) ? sums[t - off] : 0u;
        __syncthreads();
        sums[t] += v;
        __syncthreads();
    }
    uint32_t run = (t == 0) ? 0u : sums[t - 1];
    for (int k = 0; k < K; ++k){ P[base + k] = run; Cu[base + k] = run; run += c[base + k]; }
    if (t == 255) P[N] = run;
}

// ---- K4: CSR fill + QKV projections ----
__global__ void fillqkv_kernel(const int* __restrict__ eip, const int* __restrict__ ein,
                               uint32_t* __restrict__ iws, float* __restrict__ ws){
    int b = blockIdx.x;
    if (b < 768){
        int e = b * 256 + threadIdx.x;
        if (e >= Eg) return;
        uint32_t* Cu  = iws + OI_CUR;
        uint32_t* Pay = iws + OI_PAY;
        int rp = clampi(eip[e]), cp = clampi(eip[Eg + e]);
        int rn = clampi(ein[e]), cn = clampi(ein[Eg + e]);
        uint32_t p;
        p = atomicAdd(&Cu[0 * N + rp], 1u); if (p < Eg) Pay[0 * (size_t)Eg + p] = (uint32_t)e | ((uint32_t)cp << 18);
        p = atomicAdd(&Cu[1 * N + cp], 1u); if (p < Eg) Pay[1 * (size_t)Eg + p] = (uint32_t)e | ((uint32_t)rp << 18);
        p = atomicAdd(&Cu[2 * N + rn], 1u); if (p < Eg) Pay[2 * (size_t)Eg + p] = (uint32_t)e | ((uint32_t)cn << 18);
        p = atomicAdd(&Cu[3 * N + cn], 1u); if (p < Eg) Pay[3 * (size_t)Eg + p] = (uint32_t)e | ((uint32_t)rn << 18);
    } else {
        int bb = b - 768;
        int m = bb / 1536, ib = bb - m * 1536;
        int wid = threadIdx.x >> 6, lane = threadIdx.x & 63;
        int i = ib * 4 + wid;
        const float* x = ws + OF_XF + (m < 3 ? 0 : NF) + (size_t)i * 64;
        const float* W = ws + OF_WA + (size_t)m * 4096;
        float xreg = x[lane];
        float acc = ws[OF_BA + m * 64 + lane];
        #pragma unroll 16
        for (int d = 0; d < 64; ++d)
            acc += __shfl(xreg, d, 64) * W[d * 64 + lane];
        acc = sane(acc);
        if (m == 0 || m == 3) acc *= 0.125f;   // fold softmax scale into Q
        bf* qkvb = (bf*)(ws + OF_QKVB);
        qkvb[(size_t)m * NF + (size_t)i * 64 + lane] = __float2bfloat16(acc);
    }
}

// ---- K5: V -> V^T (bf16), 64x64 LDS tiles (verified round 7) ----
__global__ void transpose_kernel(float* __restrict__ ws){
    const bf* qkvb = (const bf*)(ws + OF_QKVB);
    bf* vt = (bf*)(ws + OF_VT);
    int b = blockIdx.x;               // 0..191
    int sg = b / 96, tile = b - sg * 96;
    const bf* Vb = qkvb + (size_t)(sg * 3 + 2) * NF;
    bf* Vt = vt + (size_t)sg * 64 * N;
    __shared__ short T[64][72];
    int t = threadIdx.x;
    int row = t >> 2, ch = t & 3;
    const short* src = (const short*)(Vb + (size_t)(tile * 64 + row) * 64 + ch * 16);
    short8 a = *(const short8*)src;
    short8 c = *(const short8*)(src + 8);
    #pragma unroll
    for (int j = 0; j < 8; ++j){ T[row][ch * 16 + j] = a[j]; T[row][ch * 16 + 8 + j] = c[j]; }
    __syncthreads();
    int d = t >> 2;
    short8 o0, o1;
    #pragma unroll
    for (int j = 0; j < 8; ++j){ o0[j] = T[ch * 16 + j][d]; o1[j] = T[ch * 16 + 8 + j][d]; }
    short* dst = (short*)(Vt + (size_t)d * N + tile * 64 + ch * 16);
    *(short8*)dst = o0;
    *(short8*)(dst + 8) = o1;
}

// ---- K6: dense unmasked attention. K staged in LDS (pitch 66, granule
// interleave — correctness verified round 8); V^T fragments straight from
// global (addresses tile-invariant -> hoisted, latency hidden); P wave-private
// LDS round-trip. Atomic (O,l) merge with cs=4 (round-6 proven traffic).
__global__ void __launch_bounds__(256, 4)
attn_dense_kernel(const float* __restrict__ ws_ro, float* __restrict__ O,
                  float* __restrict__ Lg){
    __shared__ __align__(16) short Kl[64 * 66];    // [col][k granule-interleaved]
    __shared__ __align__(16) float Pl[4][16 * 33]; // per-wave P round-trip

    int tid = threadIdx.x, lane = tid & 63, wv = tid >> 6;
    int m16 = lane & 15, quad = lane >> 4;
    int rt = blockIdx.x, cs = blockIdx.y, sg = blockIdx.z;
    const bf* qkvb = (const bf*)(ws_ro + OF_QKVB);
    const bf* Qb = qkvb + (size_t)(sg * 3) * NF;
    const bf* Kb = Qb + NF;
    const bf* Vt = (const bf*)(ws_ro + OF_VT) + (size_t)sg * 64 * N;

    int rowbase = rt * 64 + wv * 16;
    short8 Qf0 = *(const short8*)(Qb + (size_t)(rowbase + m16) * 64 + quad * 8);
    short8 Qf1 = *(const short8*)(Qb + (size_t)(rowbase + m16) * 64 + 32 + quad * 8);

    float4v Oc[4];
    #pragma unroll
    for (int t = 0; t < 4; ++t) Oc[t] = (float4v){0.f, 0.f, 0.f, 0.f};
    float l = 0.f;

    int scol = tid & 63, sgrp = tid >> 6;
    int g0 = 2 * sgrp, g1 = g0 + 1;
    int posK0 = (g0 & 3) * 16 + (g0 >> 2) * 8;
    int posK1 = (g1 & 3) * 16 + (g1 >> 2) * 8;
    int posA = ((2 * quad) & 3) * 8 + ((2 * quad) >> 2) * 4;
    int posB = ((2 * quad + 1) & 3) * 8 + ((2 * quad + 1) >> 2) * 4;

    int c0 = cs * (N / 4);
    const short* ksrc = (const short*)(Kb + (size_t)(c0 + scol) * 64 + sgrp * 16);
    short8 ka = *(const short8*)ksrc, kc = *(const short8*)(ksrc + 8);

    for (int cb = c0; cb < c0 + N / 4; cb += 64){
        *(short8*)(&Kl[scol * 66 + posK0]) = ka;
        *(short8*)(&Kl[scol * 66 + posK1]) = kc;
        if (cb + 64 < c0 + N / 4){
            const short* kn = (const short*)(Kb + (size_t)(cb + 64 + scol) * 64 + sgrp * 16);
            ka = *(const short8*)kn; kc = *(const short8*)(kn + 8);
        }
        __syncthreads();

        float* Pw = Pl[wv];
        #pragma unroll
        for (int kg = 0; kg < 2; ++kg){
            #pragma unroll
            for (int ct = 0; ct < 2; ++ct){
                int colt = kg * 32 + ct * 16;
                short8 A0 = *(const short8*)(&Kl[(colt + m16) * 66 + quad * 16]);
                short8 A1 = *(const short8*)(&Kl[(colt + m16) * 66 + quad * 16 + 8]);
                float4v s = __builtin_amdgcn_mfma_f32_16x16x32_bf16(
                                A0, Qf0, (float4v){0.f,0.f,0.f,0.f}, 0, 0, 0);
                s = __builtin_amdgcn_mfma_f32_16x16x32_bf16(A1, Qf1, s, 0, 0, 0);
                float4v pv;
                #pragma unroll
                for (int r = 0; r < 4; ++r){
                    pv[r] = __expf(s[r] + 1.0f);
                    l += pv[r];
                }
                *(float4v*)(&Pw[m16 * 33 + quad * 8 + ct * 4]) = pv;
            }
            asm volatile("s_waitcnt lgkmcnt(0)" ::: "memory");
            float4v pa = *(const float4v*)(&Pw[m16 * 33 + posA]);
            float4v pb = *(const float4v*)(&Pw[m16 * 33 + posB]);
            short8 Pf;
            #pragma unroll
            for (int j = 0; j < 4; ++j){ Pf[j] = f2b(pa[j]); Pf[4 + j] = f2b(pb[j]); }
            #pragma unroll
            for (int dt = 0; dt < 4; ++dt){
                short8 Va = *(const short8*)(Vt + (size_t)(dt * 16 + m16) * N + cb + kg * 32 + quad * 8);
                Oc[dt] = __builtin_amdgcn_mfma_f32_16x16x32_bf16(Va, Pf, Oc[dt], 0, 0, 0);
            }
        }
        __syncthreads();
    }
    l += __shfl_xor(l, 16, 64);
    l += __shfl_xor(l, 32, 64);
    if (quad == 0) atomicAdd(&Lg[(size_t)sg * N + rowbase + m16], l);
    float* Op = O + ((size_t)sg * N + rowbase + m16) * 64;
    #pragma unroll
    for (int dt = 0; dt < 4; ++dt)
        #pragma unroll
        for (int r = 0; r < 4; ++r)
            atomicAdd(&Op[dt * 16 + quad * 4 + r], Oc[dt][r]);
}

// ---- mega kernel roles (verified round 6) ----
__device__ __forceinline__ void mean_role(int b, const uint32_t* __restrict__ iws,
                                          const float* __restrict__ ws_ro, float* __restrict__ ws){
    int wid = threadIdx.x >> 6, d = threadIdx.x & 63;
    int gw = b * 4 + wid;
    int sign = gw >= N;
    int i = gw - sign * N;
    const float* x = ws_ro + OF_XF + (size_t)sign * NF;
    int csr = sign ? 2 : 0;
    const uint32_t* P   = iws + OI_PTR + (size_t)csr * (N + 1);
    const uint32_t* Pay = iws + OI_PAY + (size_t)csr * Eg;
    float acc = x[(size_t)i * 64 + d];
    uint32_t p0 = P[i], p1 = P[i + 1];
    if (p1 > (uint32_t)Eg) p1 = Eg;
    if (p0 > p1) p0 = p1;
    uint32_t p = p0;
    for (; p + 4 <= p1; p += 4){
        int c0 = (int)(Pay[p]     >> 18);
        int c1 = (int)(Pay[p + 1] >> 18);
        int c2 = (int)(Pay[p + 2] >> 18);
        int c3 = (int)(Pay[p + 3] >> 18);
        float a0 = x[(size_t)c0 * 64 + d], a1 = x[(size_t)c1 * 64 + d];
        float a2 = x[(size_t)c2 * 64 + d], a3 = x[(size_t)c3 * 64 + d];
        acc += (a0 + a1) + (a2 + a3);
    }
    for (; p < p1; ++p)
        acc += x[(size_t)(Pay[p] >> 18) * 64 + d];
    ws[OF_MEAN + (size_t)sign * NF + (size_t)i * 64 + d] = sane(acc / (float)(p1 - p0 + 1));
}

__device__ __forceinline__ void pool_role(int b, const void* __restrict__ efp,
                                          const void* __restrict__ efn,
                                          const uint32_t* __restrict__ iws,
                                          uint32_t fB, float* __restrict__ ws){
    int wid = threadIdx.x >> 6, lane = threadIdx.x & 63;
    int gw = b * 4 + wid;
    int g = gw / N, i = gw - g * N;
    const void* ef = (g < 2) ? efp : efn;
    const uint32_t* P   = iws + OI_PTR + (size_t)g * (N + 1);
    const uint32_t* Pay = iws + OI_PAY + (size_t)g * Eg;
    int f = lane & 31, h = lane >> 5;
    float m = 0.f;
    uint32_t p0 = P[i], p1 = P[i + 1];
    if (p1 > (uint32_t)Eg) p1 = Eg;
    if (p0 > p1) p0 = p1;
    uint32_t p = p0 + h;
    if (fB){
        const float* E = (const float*)ef;
        for (; p + 2 < p1; p += 4){
            uint32_t e0 = Pay[p] & 0x3FFFFu, e1 = Pay[p + 2] & 0x3FFFFu;
            m = fmaxf(m, fmaxf(E[(size_t)e0 * 32 + f], E[(size_t)e1 * 32 + f]));
        }
        for (; p < p1; p += 2)
            m = fmaxf(m, E[(size_t)(Pay[p] & 0x3FFFFu) * 32 + f]);
    } else {
        const bf* E = (const bf*)ef;
        for (; p + 2 < p1; p += 4){
            uint32_t e0 = Pay[p] & 0x3FFFFu, e1 = Pay[p + 2] & 0x3FFFFu;
            m = fmaxf(m, fmaxf(b2f(E[(size_t)e0 * 32 + f]), b2f(E[(size_t)e1 * 32 + f])));
        }
        for (; p < p1; p += 2)
            m = fmaxf(m, b2f(E[(size_t)(Pay[p] & 0x3FFFFu) * 32 + f]));
    }
    m = fmaxf(m, __shfl_xor(m, 32, 64));
    m = sane(m);
    float ss = m * m;
    ss += __shfl_xor(ss, 16, 64); ss += __shfl_xor(ss, 8, 64);
    ss += __shfl_xor(ss, 4, 64);  ss += __shfl_xor(ss, 2, 64);
    ss += __shfl_xor(ss, 1, 64);
    float r = m / fmaxf(sqrtf(ss), 1e-12f);
    if (lane < 32) ws[OF_POOL + ((size_t)g * N + i) * 32 + f] = sane(r);
}

__device__ __forceinline__ void corr_role(int b, const uint32_t* __restrict__ iws,
                                          const float* __restrict__ ws_ro,
                                          float* __restrict__ O, float* __restrict__ Lg){
    int wid = threadIdx.x >> 6, d = threadIdx.x & 63;
    int gw = b * 4 + wid;
    int sg = gw >= N;
    int i = gw - sg * N;
    const bf* Qb = (const bf*)(ws_ro + OF_QKVB) + (size_t)(sg * 3) * NF;
    const bf* Kb = Qb + NF;
    const bf* Vb = Kb + NF;
    const int csr = sg ? 2 : 0;
    const uint32_t* Pp  = iws + OI_PTR + (size_t)csr * (N + 1);
    const uint32_t* Pay = iws + OI_PAY + (size_t)csr * Eg;
    float q = b2f(Qb[(size_t)i * 64 + d]);
    float corrO = 0.f, corrL = 0.f;
    uint32_t p0 = Pp[i], p1 = Pp[i + 1];
    if (p1 > (uint32_t)Eg) p1 = Eg;
    if (p0 > p1) p0 = p1;
    constexpr float C = 0.63212055882f;      // 1 - 1/e
    uint32_t p = p0;
    for (; p + 2 <= p1; p += 2){
        int c0 = (int)(Pay[p] >> 18), c1 = (int)(Pay[p + 1] >> 18);
        float s0 = q * b2f(Kb[(size_t)c0 * 64 + d]);
        float s1 = q * b2f(Kb[(size_t)c1 * 64 + d]);
        s0 += __shfl_xor(s0, 32, 64); s1 += __shfl_xor(s1, 32, 64);
        s0 += __shfl_xor(s0, 16, 64); s1 += __shfl_xor(s1, 16, 64);
        s0 += __shfl_xor(s0, 8, 64);  s1 += __shfl_xor(s1, 8, 64);
        s0 += __shfl_xor(s0, 4, 64);  s1 += __shfl_xor(s1, 4, 64);
        s0 += __shfl_xor(s0, 2, 64);  s1 += __shfl_xor(s1, 2, 64);
        s0 += __shfl_xor(s0, 1, 64);  s1 += __shfl_xor(s1, 1, 64);
        float f0 = C * __expf(s0 + 1.0f);
        float f1 = C * __expf(s1 + 1.0f);
        corrO += f0 * b2f(Vb[(size_t)c0 * 64 + d]) + f1 * b2f(Vb[(size_t)c1 * 64 + d]);
        corrL += f0 + f1;
    }
    for (int extra = 0; extra < 2; ++extra){
        int c;
        if (extra == 0){ if (p >= p1) continue; c = (int)(Pay[p] >> 18); }
        else c = i;                              // diagonal
        float s = q * b2f(Kb[(size_t)c * 64 + d]);
        s += __shfl_xor(s, 32, 64); s += __shfl_xor(s, 16, 64); s += __shfl_xor(s, 8, 64);
        s += __shfl_xor(s, 4, 64);  s += __shfl_xor(s, 2, 64);  s += __shfl_xor(s, 1, 64);
        float f = C * __expf(s + 1.0f);
        corrO += f * b2f(Vb[(size_t)c * 64 + d]);
        corrL += f;
    }
    atomicAdd(&O[((size_t)sg * N + i) * 64 + d], -corrO);
    if (d == 0) atomicAdd(&Lg[(size_t)sg * N + i], -corrL);
}

__global__ void mega_kernel(const void* __restrict__ efp, const void* __restrict__ efn,
                            const uint32_t* __restrict__ iws,
                            const uint32_t* __restrict__ flags, float* __restrict__ ws){
    int b = blockIdx.x;
    if (b < 3072)       mean_role(b, iws, ws, ws);
    else if (b < 9216)  pool_role(b - 3072, efp, efn, iws, flags[1], ws);
    else                corr_role(b - 9216, iws, ws, ws + OF_O, ws + OF_L);
}

// ---- K8: fused epilogue ----
__global__ void final_kernel(const uint32_t* __restrict__ flags,
                             const float* __restrict__ ws, void* __restrict__ outv){
    uint32_t fA = flags[0];
    int wid = threadIdx.x >> 6, c = threadIdx.x & 63;
    int i = blockIdx.x * 4 + wid;
    __shared__ float feat[4][384];
    __shared__ float onrm[4][64];
    for (int s = 0; s < 2; ++s){
        float osum = ws[OF_O + ((size_t)s * N + i) * 64 + c];
        float lsum = ws[OF_L + (size_t)s * N + i];
        onrm[wid][c] = sane(osum / fmaxf(lsum, 1e-20f));
        __syncthreads();
        const float* Wo = ws + OF_WO + (size_t)s * 4096;
        float attn = ws[OF_BO + s * 64 + c];
        #pragma unroll 8
        for (int d = 0; d < 64; ++d) attn += onrm[wid][d] * Wo[d * 64 + c];
        feat[wid][s * 64 + c] = sane(ws[OF_MEAN + (size_t)s * NF + (size_t)i * 64 + c] + attn);
        __syncthreads();
    }
    feat[wid][128 + c] = ws[OF_XF + (size_t)i * 64 + c];
    feat[wid][192 + c] = ws[OF_XF + NF + (size_t)i * 64 + c];
    {
        int g0 = c >> 5, f = c & 31;
        feat[wid][256 + c] = ws[OF_POOL + ((size_t)g0 * N + i) * 32 + f];
        feat[wid][320 + c] = ws[OF_POOL + ((size_t)(2 + g0) * N + i) * 32 + f];
    }
    __syncthreads();
    float acc = ws[OF_BF + c];
    #pragma unroll 8
    for (int k = 0; k < 384; ++k) acc += feat[wid][k] * ws[OF_WF + (size_t)k * 64 + c];
    acc = sane(acc);
    float ss = acc * acc;
    ss += __shfl_xor(ss, 32, 64); ss += __shfl_xor(ss, 16, 64); ss += __shfl_xor(ss, 8, 64);
    ss += __shfl_xor(ss, 4, 64);  ss += __shfl_xor(ss, 2, 64);  ss += __shfl_xor(ss, 1, 64);
    float r = acc / fmaxf(sqrtf(ss), 1e-12f);
    if (fA) ((float*)outv)[(size_t)i * 64 + c] = r;
    else    ((bf*)outv)[(size_t)i * 64 + c] = __float2bfloat16(r);
}

extern "C" void kernel_launch(void* const* d_in, const int* in_sizes, int n_in,
                              void* d_out, int out_size, void* d_ws, size_t ws_size,
                              hipStream_t stream){
    const int* eip = (const int*)d_in[2];
    const int* ein = (const int*)d_in[3];

    float* ws = (float*)d_ws;
    uint32_t* iws = (uint32_t*)(ws + F_TOTAL);
    uint32_t* flags = iws + OI_FLAG;
    float* O  = ws + OF_O;
    float* Lg = ws + OF_L;

    prep0_kernel<<<dim3(3217), 256, 0, stream>>>(d_in[0], d_in[4], d_in[6], d_in[8],
                                                 O, iws + OI_CNT, flags);
    prep1_kernel<<<dim3(4067), 256, 0, stream>>>(
        d_in[0], d_in[1],
        d_in[8],  d_in[10], d_in[12], d_in[16], d_in[18], d_in[20],
        d_in[9],  d_in[11], d_in[13], d_in[17], d_in[19], d_in[21],
        d_in[14], d_in[15], d_in[22], d_in[23],
        d_in[6],  d_in[7],
        eip, ein, flags, ws, iws);
    scan_kernel<<<4, 256, 0, stream>>>(iws);
    fillqkv_kernel<<<dim3(768 + 9216), 256, 0, stream>>>(eip, ein, iws, ws);
    transpose_kernel<<<dim3(192), 256, 0, stream>>>(ws);
    attn_dense_kernel<<<dim3(N / 64, 4, 2), 256, 0, stream>>>(ws, O, Lg);
    mega_kernel<<<dim3(12288), 256, 0, stream>>>(d_in[4], d_in[5], iws, flags, ws);
    final_kernel<<<dim3(N / 4), 256, 0, stream>>>(flags, ws, d_out);
}